// Round 9
// baseline (754.275 us; speedup 1.0000x reference)
//
#include <hip/hip_runtime.h>

#define NROWS 300000
#define NBLK ((NROWS + 63) / 64)

typedef float f32x4 __attribute__((ext_vector_type(4)));
typedef short s16x8 __attribute__((ext_vector_type(8)));
typedef unsigned short u16x8 __attribute__((ext_vector_type(8)));
typedef unsigned short u16x4 __attribute__((ext_vector_type(4)));

__device__ __forceinline__ float bf2f(unsigned short u) {
    return __uint_as_float(((unsigned)u) << 16);
}
__device__ __forceinline__ unsigned short f2bf(float f) {
    unsigned u = __float_as_uint(f);
    u += 0x7FFFu + ((u >> 16) & 1u);   // round-to-nearest-even
    return (unsigned short)(u >> 16);
}

// ---------------------------------------------------------------------------
// prep: x (f32) -> xb (bf16) grid-stride; first 144 blocks also transpose
// W[k][c][d] f32 -> WT[k][d][c] bf16 for both convs.
// ---------------------------------------------------------------------------
__global__ __launch_bounds__(256) void prep(const float* __restrict__ x,
                                            unsigned short* __restrict__ xb,
                                            const float* __restrict__ W1,
                                            const float* __restrict__ W2,
                                            unsigned short* __restrict__ WT1,
                                            unsigned short* __restrict__ WT2) {
    const int i0 = blockIdx.x * 256 + threadIdx.x;
    if (i0 < 9 * 4096) {
        const int k = i0 >> 12, cc = (i0 >> 6) & 63, d = i0 & 63;
        const int o = k * 4096 + d * 64 + cc;
        WT1[o] = f2bf(W1[i0]);
        WT2[o] = f2bf(W2[i0]);
    }
    const int NQ = NROWS * 8;
    for (int i = i0; i < NQ; i += gridDim.x * 256) {
        const f32x4 v0 = *(const f32x4*)(x + (size_t)i * 8);
        const f32x4 v1 = *(const f32x4*)(x + (size_t)i * 8 + 4);
        u16x8 o;
        o[0] = f2bf(v0[0]); o[1] = f2bf(v0[1]); o[2] = f2bf(v0[2]); o[3] = f2bf(v0[3]);
        o[4] = f2bf(v1[0]); o[5] = f2bf(v1[1]); o[6] = f2bf(v1[2]); o[7] = f2bf(v1[3]);
        *(u16x8*)(xb + (size_t)i * 8) = o;   // cached: conv1 gathers this
    }
}

// ---------------------------------------------------------------------------
// Gathered GEMM via MFMA 16x16x32 bf16 (r2 structure: fastest measured; the
// gather is pinned by the chip's random-request rate, not staging structure).
// CONV==2 folds relu(v*s1+b1) into the A-fragment path.
// Fused BN stats: per-thread sum/sumsq -> shfl over kg -> LDS over waves ->
// ONE coalesced 128-float partial row per block (NO atomics - r7 lesson:
// 4688-contender same-address atomics cost ~60us).
// A-frag: lane l holds G[row = l&15][c = ch*32 + (l>>4)*8 + j], gathered.
// B-frag: lane l holds W[c][d = dj*16 + (l&15)] from WT[k][d][c].
// D-frag: lane l reg r -> row (l>>4)*4+r, col dj*16 + (l&15).
// ---------------------------------------------------------------------------
template <int CONV>
__global__ __launch_bounds__(256) void conv_mfma(const unsigned short* __restrict__ xb,
                                                 const int* __restrict__ nbrs,
                                                 const unsigned short* __restrict__ WT,
                                                 const float* __restrict__ sb,
                                                 unsigned short* __restrict__ outb,
                                                 float* __restrict__ P) {
    __shared__ float SSum[4][64];
    __shared__ float SSq[4][64];

    const int tid = threadIdx.x;
    const int l = tid & 63;
    const int w = tid >> 6;
    const int lr = l & 15;
    const int kg = l >> 4;
    const int c00 = kg * 8;

    const int rowA = blockIdx.x * 64 + w * 16 + lr;
    const int rowAc = rowA < NROWS ? rowA : NROWS - 1;

    // BN1 scale/bias for this lane's A-channels (conv2 only)
    float s0r[8], b0r[8], s1r[8], b1r[8];
    if (CONV == 2) {
#pragma unroll
        for (int j = 0; j < 8; ++j) {
            s0r[j] = sb[c00 + j];       b0r[j] = sb[64 + c00 + j];
            s1r[j] = sb[32 + c00 + j];  b1r[j] = sb[96 + c00 + j];
        }
    }

    int nb[9];
#pragma unroll
    for (int k = 0; k < 9; ++k) nb[k] = nbrs[rowAc * 9 + k];

    s16x8 raw0[9], raw1[9];
#pragma unroll
    for (int k = 0; k < 9; ++k) {
        const unsigned short* rp = xb + (size_t)nb[k] * 64 + c00;
        raw0[k] = *(const s16x8*)rp;        // channels [c00, c00+8)
        raw1[k] = *(const s16x8*)(rp + 32); // channels [c00+32, c00+40)
    }

    f32x4 acc[4];
#pragma unroll
    for (int d = 0; d < 4; ++d) {
        acc[d][0] = 0.f; acc[d][1] = 0.f; acc[d][2] = 0.f; acc[d][3] = 0.f;
    }

#pragma unroll
    for (int k = 0; k < 9; ++k) {
        s16x8 a0 = raw0[k], a1 = raw1[k];
        if (CONV == 2) {
#pragma unroll
            for (int j = 0; j < 8; ++j) {
                const float f0 = fmaxf(bf2f((unsigned short)a0[j]) * s0r[j] + b0r[j], 0.f);
                const float f1 = fmaxf(bf2f((unsigned short)a1[j]) * s1r[j] + b1r[j], 0.f);
                a0[j] = (short)f2bf(f0);
                a1[j] = (short)f2bf(f1);
            }
        }
        const unsigned short* wp = WT + k * 4096 + lr * 64 + c00;
#pragma unroll
        for (int dj = 0; dj < 4; ++dj) {
            const s16x8 b0 = *(const s16x8*)(wp + dj * 1024);        // ch 0..31 slice
            const s16x8 b1 = *(const s16x8*)(wp + dj * 1024 + 32);   // ch 32..63 slice
            acc[dj] = __builtin_amdgcn_mfma_f32_16x16x32_bf16(a0, b0, acc[dj], 0, 0, 0);
            acc[dj] = __builtin_amdgcn_mfma_f32_16x16x32_bf16(a1, b1, acc[dj], 0, 0, 0);
        }
    }

    // epilogue: store + fused per-channel partial stats (channel c = dj*16+lr)
    const int orow0 = blockIdx.x * 64 + w * 16 + kg * 4;
#pragma unroll
    for (int dj = 0; dj < 4; ++dj) {
        float sm = 0.f, sq = 0.f;
#pragma unroll
        for (int r = 0; r < 4; ++r) {
            const int orow = orow0 + r;
            if (orow < NROWS) {
                const float v = acc[dj][r];
                outb[(size_t)orow * 64 + dj * 16 + lr] = f2bf(v);
                sm += v; sq += v * v;
            }
        }
        sm += __shfl_xor(sm, 16); sm += __shfl_xor(sm, 32);
        sq += __shfl_xor(sq, 16); sq += __shfl_xor(sq, 32);
        if (kg == 0) { SSum[w][dj * 16 + lr] = sm; SSq[w][dj * 16 + lr] = sq; }
    }
    __syncthreads();
    if (tid < 128) {   // one coalesced 512-B partial row per block
        const int c = tid & 63;
        const float v = (tid < 64)
            ? SSum[0][c] + SSum[1][c] + SSum[2][c] + SSum[3][c]
            : SSq[0][c] + SSq[1][c] + SSq[2][c] + SSq[3][c];
        P[(size_t)blockIdx.x * 128 + tid] = v;
    }
}

// ---------------------------------------------------------------------------
// Reduce NBLK partial rows + fold into per-channel scale/shift: f = v*s + b
// 1024 threads: 8 slices x 128 columns, coalesced 512-B rows per iteration.
// ---------------------------------------------------------------------------
__global__ __launch_bounds__(1024) void bn_finalize(const float* __restrict__ P,
                                                    const float* __restrict__ gamma,
                                                    const float* __restrict__ beta,
                                                    float* __restrict__ sb) {
    __shared__ float red[8][128];
    const int t = threadIdx.x;
    const int c = t & 127;
    const int s = t >> 7;
    float a = 0.f;
    for (int p = s; p < NBLK; p += 8) a += P[(size_t)p * 128 + c];
    red[s][c] = a;
    __syncthreads();
    if (t < 128) {
        float tot = 0.f;
#pragma unroll
        for (int i = 0; i < 8; ++i) tot += red[i][t];
        red[0][t] = tot;
    }
    __syncthreads();
    if (t < 64) {
        const float mean = red[0][t] * (1.0f / NROWS);
        const float var = red[0][64 + t] * (1.0f / NROWS) - mean * mean;
        const float sc = gamma[t] * rsqrtf(var + 1e-5f);
        sb[t] = sc;
        sb[64 + t] = beta[t] - mean * sc;
    }
}

// ---------------------------------------------------------------------------
// out = relu(out2*s2 + b2 + x), f32 output (nt 16-B stores: write-granular
// safe, keeps caches clean; the 2-B nt stores of r8 write-amplified 2.3x).
// ---------------------------------------------------------------------------
__global__ __launch_bounds__(256) void final_out(const unsigned short* __restrict__ o2,
                                                 const float* __restrict__ x,
                                                 const float* __restrict__ sb,
                                                 float* __restrict__ out) {
    const int NQ = NROWS * 16;
    for (int i = blockIdx.x * 256 + threadIdx.x; i < NQ; i += gridDim.x * 256) {
        const int c4 = (i & 15) * 4;
        const u16x4 v = *(const u16x4*)(o2 + (size_t)i * 4);
        const f32x4 xv = *(const f32x4*)(x + (size_t)i * 4);
        const f32x4 s = *(const f32x4*)(sb + c4);
        const f32x4 b = *(const f32x4*)(sb + 64 + c4);
        f32x4 o;
        o[0] = fmaxf(bf2f(v[0]) * s[0] + b[0] + xv[0], 0.f);
        o[1] = fmaxf(bf2f(v[1]) * s[1] + b[1] + xv[1], 0.f);
        o[2] = fmaxf(bf2f(v[2]) * s[2] + b[2] + xv[2], 0.f);
        o[3] = fmaxf(bf2f(v[3]) * s[3] + b[3] + xv[3], 0.f);
        __builtin_nontemporal_store(o, (f32x4*)(out + (size_t)i * 4));
    }
}

extern "C" void kernel_launch(void* const* d_in, const int* in_sizes, int n_in,
                              void* d_out, int out_size, void* d_ws, size_t ws_size,
                              hipStream_t stream) {
    const float* x      = (const float*)d_in[0];
    const int*   nbrs   = (const int*)d_in[1];
    const float* W1     = (const float*)d_in[2];
    const float* gamma1 = (const float*)d_in[3];
    const float* beta1  = (const float*)d_in[4];
    const float* W2     = (const float*)d_in[5];
    const float* gamma2 = (const float*)d_in[6];
    const float* beta2  = (const float*)d_in[7];
    float* out = (float*)d_out;

    // ws layout (~41 MB): out2 bf16 | WT1 | WT2 | P1 | P2 | sb1 | sb2
    char* ws = (char*)d_ws;
    unsigned short* out2b = (unsigned short*)ws;                        // 38,400,000 B
    unsigned short* WT1   = (unsigned short*)(ws + 38400000);           // 73,728 B
    unsigned short* WT2   = (unsigned short*)(ws + 38400000 + 73728);   // 73,728 B
    float* P1  = (float*)(ws + 38400000 + 147456);                      // 2,400,256 B
    float* P2  = P1 + (size_t)NBLK * 128;                               // 2,400,256 B
    float* sb1 = P2 + (size_t)NBLK * 128;
    float* sb2 = sb1 + 128;
    // d_out doubles as scratch until final_out rewrites it:
    //   front half: out1b (bf16, 38.4 MB), back half: xb (bf16, 38.4 MB)
    unsigned short* out1b = (unsigned short*)d_out;
    unsigned short* xb    = (unsigned short*)d_out + 19200000;

    prep<<<2048, 256, 0, stream>>>(x, xb, W1, W2, WT1, WT2);
    conv_mfma<1><<<NBLK, 256, 0, stream>>>(xb, nbrs, WT1, nullptr, out1b, P1);
    bn_finalize<<<1, 1024, 0, stream>>>(P1, gamma1, beta1, sb1);
    conv_mfma<2><<<NBLK, 256, 0, stream>>>(out1b, nbrs, WT2, sb1, out2b, P2);
    bn_finalize<<<1, 1024, 0, stream>>>(P2, gamma2, beta2, sb2);
    final_out<<<2048, 256, 0, stream>>>(out2b, x, sb2, out);
}

// Round 10
// 482.124 us; speedup vs baseline: 1.5645x; 1.5645x over previous
//
#include <hip/hip_runtime.h>

#define NROWS 300000
#define NBLK ((NROWS + 63) / 64)

typedef float f32x4 __attribute__((ext_vector_type(4)));
typedef short s16x8 __attribute__((ext_vector_type(8)));
typedef unsigned short u16x8 __attribute__((ext_vector_type(8)));
typedef unsigned short u16x4 __attribute__((ext_vector_type(4)));

__device__ __forceinline__ float bf2f(unsigned short u) {
    return __uint_as_float(((unsigned)u) << 16);
}
__device__ __forceinline__ unsigned short f2bf(float f) {
    unsigned u = __float_as_uint(f);
    u += 0x7FFFu + ((u >> 16) & 1u);   // round-to-nearest-even
    return (unsigned short)(u >> 16);
}

// ---------------------------------------------------------------------------
// prep: x (f32) -> xb (bf16) grid-stride; first 144 blocks also transpose
// W[k][c][d] f32 -> WT[k][d][c] bf16 for both convs.
// ---------------------------------------------------------------------------
__global__ __launch_bounds__(256) void prep(const float* __restrict__ x,
                                            unsigned short* __restrict__ xb,
                                            const float* __restrict__ W1,
                                            const float* __restrict__ W2,
                                            unsigned short* __restrict__ WT1,
                                            unsigned short* __restrict__ WT2) {
    const int i0 = blockIdx.x * 256 + threadIdx.x;
    if (i0 < 9 * 4096) {
        const int k = i0 >> 12, cc = (i0 >> 6) & 63, d = i0 & 63;
        const int o = k * 4096 + d * 64 + cc;
        WT1[o] = f2bf(W1[i0]);
        WT2[o] = f2bf(W2[i0]);
    }
    const int NQ = NROWS * 8;
    for (int i = i0; i < NQ; i += gridDim.x * 256) {
        const f32x4 v0 = *(const f32x4*)(x + (size_t)i * 8);
        const f32x4 v1 = *(const f32x4*)(x + (size_t)i * 8 + 4);
        u16x8 o;
        o[0] = f2bf(v0[0]); o[1] = f2bf(v0[1]); o[2] = f2bf(v0[2]); o[3] = f2bf(v0[3]);
        o[4] = f2bf(v1[0]); o[5] = f2bf(v1[1]); o[6] = f2bf(v1[2]); o[7] = f2bf(v1[3]);
        *(u16x8*)(xb + (size_t)i * 8) = o;   // cached: conv1 gathers this
    }
}

// ---------------------------------------------------------------------------
// Gathered GEMM via MFMA 16x16x32 bf16 (r2 structure: fastest measured; the
// gather is pinned at ~12G random 64-B transactions/s chip-wide regardless
// of staging structure - 6 variants measured identical).
// CONV==2 folds relu(v*s1+b1) into the A-fragment path.
// Fused BN stats: per-thread sum/sumsq -> shfl over kg -> LDS over waves ->
// ONE coalesced 128-float partial row per block (no atomics, no extra pass).
// A-frag: lane l holds G[row = l&15][c = ch*32 + (l>>4)*8 + j], gathered.
// B-frag: lane l holds W[c][d = dj*16 + (l&15)] from WT[k][d][c].
// D-frag: lane l reg r -> row (l>>4)*4+r, col dj*16 + (l&15).
// ---------------------------------------------------------------------------
template <int CONV>
__global__ __launch_bounds__(256) void conv_mfma(const unsigned short* __restrict__ xb,
                                                 const int* __restrict__ nbrs,
                                                 const unsigned short* __restrict__ WT,
                                                 const float* __restrict__ sb,
                                                 unsigned short* __restrict__ outb,
                                                 float* __restrict__ P) {
    __shared__ float SSum[4][64];
    __shared__ float SSq[4][64];

    const int tid = threadIdx.x;
    const int l = tid & 63;
    const int w = tid >> 6;
    const int lr = l & 15;
    const int kg = l >> 4;
    const int c00 = kg * 8;

    const int rowA = blockIdx.x * 64 + w * 16 + lr;
    const int rowAc = rowA < NROWS ? rowA : NROWS - 1;

    // BN1 scale/bias for this lane's A-channels (conv2 only)
    float s0r[8], b0r[8], s1r[8], b1r[8];
    if (CONV == 2) {
#pragma unroll
        for (int j = 0; j < 8; ++j) {
            s0r[j] = sb[c00 + j];       b0r[j] = sb[64 + c00 + j];
            s1r[j] = sb[32 + c00 + j];  b1r[j] = sb[96 + c00 + j];
        }
    }

    int nb[9];
#pragma unroll
    for (int k = 0; k < 9; ++k) nb[k] = nbrs[rowAc * 9 + k];

    s16x8 raw0[9], raw1[9];
#pragma unroll
    for (int k = 0; k < 9; ++k) {
        const unsigned short* rp = xb + (size_t)nb[k] * 64 + c00;
        raw0[k] = *(const s16x8*)rp;        // channels [c00, c00+8)
        raw1[k] = *(const s16x8*)(rp + 32); // channels [c00+32, c00+40)
    }

    f32x4 acc[4];
#pragma unroll
    for (int d = 0; d < 4; ++d) {
        acc[d][0] = 0.f; acc[d][1] = 0.f; acc[d][2] = 0.f; acc[d][3] = 0.f;
    }

#pragma unroll
    for (int k = 0; k < 9; ++k) {
        s16x8 a0 = raw0[k], a1 = raw1[k];
        if (CONV == 2) {
#pragma unroll
            for (int j = 0; j < 8; ++j) {
                const float f0 = fmaxf(bf2f((unsigned short)a0[j]) * s0r[j] + b0r[j], 0.f);
                const float f1 = fmaxf(bf2f((unsigned short)a1[j]) * s1r[j] + b1r[j], 0.f);
                a0[j] = (short)f2bf(f0);
                a1[j] = (short)f2bf(f1);
            }
        }
        const unsigned short* wp = WT + k * 4096 + lr * 64 + c00;
#pragma unroll
        for (int dj = 0; dj < 4; ++dj) {
            const s16x8 b0 = *(const s16x8*)(wp + dj * 1024);        // ch 0..31 slice
            const s16x8 b1 = *(const s16x8*)(wp + dj * 1024 + 32);   // ch 32..63 slice
            acc[dj] = __builtin_amdgcn_mfma_f32_16x16x32_bf16(a0, b0, acc[dj], 0, 0, 0);
            acc[dj] = __builtin_amdgcn_mfma_f32_16x16x32_bf16(a1, b1, acc[dj], 0, 0, 0);
        }
    }

    // epilogue: store + fused per-channel partial stats (channel c = dj*16+lr)
    const int orow0 = blockIdx.x * 64 + w * 16 + kg * 4;
#pragma unroll
    for (int dj = 0; dj < 4; ++dj) {
        float sm = 0.f, sq = 0.f;
#pragma unroll
        for (int r = 0; r < 4; ++r) {
            const int orow = orow0 + r;
            if (orow < NROWS) {
                const float v = acc[dj][r];
                outb[(size_t)orow * 64 + dj * 16 + lr] = f2bf(v);
                sm += v; sq += v * v;
            }
        }
        sm += __shfl_xor(sm, 16); sm += __shfl_xor(sm, 32);
        sq += __shfl_xor(sq, 16); sq += __shfl_xor(sq, 32);
        if (kg == 0) { SSum[w][dj * 16 + lr] = sm; SSq[w][dj * 16 + lr] = sq; }
    }
    __syncthreads();
    if (tid < 128) {   // one coalesced 512-B partial row per block
        const int c = tid & 63;
        const float v = (tid < 64)
            ? SSum[0][c] + SSum[1][c] + SSum[2][c] + SSum[3][c]
            : SSq[0][c] + SSq[1][c] + SSq[2][c] + SSq[3][c];
        P[(size_t)blockIdx.x * 128 + tid] = v;
    }
}

// ---------------------------------------------------------------------------
// Stats reduce stage 1: 128 blocks grid-stride over the NBLK partial rows,
// each block emits one 128-f32 row (parallel, coalesced - r9's single-block
// reduce over 2.4MB was ~140us of cross-XCD latency).
// ---------------------------------------------------------------------------
__global__ __launch_bounds__(128) void bn_reduce(const float* __restrict__ P,
                                                 float* __restrict__ Q) {
    const int t = threadIdx.x;   // 0..127 = column
    float a = 0.f;
    for (int p = blockIdx.x; p < NBLK; p += gridDim.x)
        a += P[(size_t)p * 128 + t];
    Q[(size_t)blockIdx.x * 128 + t] = a;
}

// ---------------------------------------------------------------------------
// Stats reduce stage 2 (64KB, one block) + fold: f = v*s + b
// ---------------------------------------------------------------------------
__global__ __launch_bounds__(128) void bn_finalize(const float* __restrict__ Q,
                                                   const float* __restrict__ gamma,
                                                   const float* __restrict__ beta,
                                                   float* __restrict__ sb) {
    __shared__ float tot[128];
    const int t = threadIdx.x;   // 0..127
    float a = 0.f;
#pragma unroll 4
    for (int p = 0; p < 128; ++p) a += Q[(size_t)p * 128 + t];
    tot[t] = a;
    __syncthreads();
    if (t < 64) {
        const float mean = tot[t] * (1.0f / NROWS);
        const float var = tot[64 + t] * (1.0f / NROWS) - mean * mean;
        const float sc = gamma[t] * rsqrtf(var + 1e-5f);
        sb[t] = sc;
        sb[64 + t] = beta[t] - mean * sc;
    }
}

// ---------------------------------------------------------------------------
// out = relu(out2*s2 + b2 + x), f32 output (nt 16-B stores: write-granular
// safe; the 2-B nt stores of r8 write-amplified 2.3x).
// ---------------------------------------------------------------------------
__global__ __launch_bounds__(256) void final_out(const unsigned short* __restrict__ o2,
                                                 const float* __restrict__ x,
                                                 const float* __restrict__ sb,
                                                 float* __restrict__ out) {
    const int NQ = NROWS * 16;
    for (int i = blockIdx.x * 256 + threadIdx.x; i < NQ; i += gridDim.x * 256) {
        const int c4 = (i & 15) * 4;
        const u16x4 v = *(const u16x4*)(o2 + (size_t)i * 4);
        const f32x4 xv = *(const f32x4*)(x + (size_t)i * 4);
        const f32x4 s = *(const f32x4*)(sb + c4);
        const f32x4 b = *(const f32x4*)(sb + 64 + c4);
        f32x4 o;
        o[0] = fmaxf(bf2f(v[0]) * s[0] + b[0] + xv[0], 0.f);
        o[1] = fmaxf(bf2f(v[1]) * s[1] + b[1] + xv[1], 0.f);
        o[2] = fmaxf(bf2f(v[2]) * s[2] + b[2] + xv[2], 0.f);
        o[3] = fmaxf(bf2f(v[3]) * s[3] + b[3] + xv[3], 0.f);
        __builtin_nontemporal_store(o, (f32x4*)(out + (size_t)i * 4));
    }
}

extern "C" void kernel_launch(void* const* d_in, const int* in_sizes, int n_in,
                              void* d_out, int out_size, void* d_ws, size_t ws_size,
                              hipStream_t stream) {
    const float* x      = (const float*)d_in[0];
    const int*   nbrs   = (const int*)d_in[1];
    const float* W1     = (const float*)d_in[2];
    const float* gamma1 = (const float*)d_in[3];
    const float* beta1  = (const float*)d_in[4];
    const float* W2     = (const float*)d_in[5];
    const float* gamma2 = (const float*)d_in[6];
    const float* beta2  = (const float*)d_in[7];
    float* out = (float*)d_out;

    // ws layout (~41 MB): out2 bf16 | WT1 | WT2 | P1 | P2 | Q | sb1 | sb2
    char* ws = (char*)d_ws;
    unsigned short* out2b = (unsigned short*)ws;                        // 38,400,000 B
    unsigned short* WT1   = (unsigned short*)(ws + 38400000);           // 73,728 B
    unsigned short* WT2   = (unsigned short*)(ws + 38400000 + 73728);   // 73,728 B
    float* P1  = (float*)(ws + 38400000 + 147456);                      // 2,400,256 B
    float* P2  = P1 + (size_t)NBLK * 128;                               // 2,400,256 B
    float* Q   = P2 + (size_t)NBLK * 128;                               // 65,536 B
    float* sb1 = Q + 128 * 128;
    float* sb2 = sb1 + 128;
    // d_out doubles as scratch until final_out rewrites it:
    //   front half: out1b (bf16, 38.4 MB), back half: xb (bf16, 38.4 MB)
    unsigned short* out1b = (unsigned short*)d_out;
    unsigned short* xb    = (unsigned short*)d_out + 19200000;

    prep<<<2048, 256, 0, stream>>>(x, xb, W1, W2, WT1, WT2);
    conv_mfma<1><<<NBLK, 256, 0, stream>>>(xb, nbrs, WT1, nullptr, out1b, P1);
    bn_reduce<<<128, 128, 0, stream>>>(P1, Q);
    bn_finalize<<<1, 128, 0, stream>>>(Q, gamma1, beta1, sb1);
    conv_mfma<2><<<NBLK, 256, 0, stream>>>(out1b, nbrs, WT2, sb1, out2b, P2);
    bn_reduce<<<128, 128, 0, stream>>>(P2, Q);
    bn_finalize<<<1, 128, 0, stream>>>(Q, gamma2, beta2, sb2);
    final_out<<<2048, 256, 0, stream>>>(out2b, x, sb2, out);
}